// Round 2
// baseline (42829.205 us; speedup 1.0000x reference)
//
#include <hip/hip_runtime.h>
#include <math.h>

// Problem constants (match reference)
#define BB   32
#define LSEQ 512
#define DD   512
#define HH   512
#define G2H  1024
#define K3H  1536

// Scan: 8 groups x 64 WGs. Group g owns batch rows 4g..4g+3. WG slot s owns
// c/innov/K cols jz=8s..8s+7 and kmid cols jm=24s..24s+23. WG = 256 thr =
// 4 waves; wave q owns col pair (2 c-cols / 6 kmid-cols) x all 4 rows.
//
// Barrier-free dataflow. Every cross-WG state word is SELF-TAGGED:
//   u32 = (gen<<16) | f16bits(value)
// Consumers spin-load (sc1, coherence point) until every word's tag equals
// the expected generation. Only dword store/load atomicity is assumed.
// Overwrite safety (2 phases of slack): a producer reaches its phase-(p+3)
// store only after observing ALL slots' phase-(p+2) words, which transitively
// requires every wave in the group to have consumed phase p.
// Polling is INCREMENTAL per batch-row (tags are monotone; a row once ready
// stays ready until this wave itself progresses) — keeps poll-loop register
// pressure low (<=6 live v4u) so __launch_bounds__(256,2) comfortably holds
// VGPR<=256 => 2 WGs/CU => all 512 WGs co-resident.
// HANG GUARD: every poll decrements a wave-uniform spin budget; on exhaustion
// the WG free-runs (garbage output, fast fail) instead of deadlocking.
#define NG   8
#define GWG  64

typedef unsigned int u32;
typedef _Float16 half2_t __attribute__((ext_vector_type(2)));
typedef u32 v4u __attribute__((ext_vector_type(4)));

// ---- coherence-point memory ops (proven pattern from prior rounds) -------
__device__ __forceinline__ void mload4(v4u& d, const u32* p) {
  asm volatile("global_load_dwordx4 %0, %1, off sc1" : "=v"(d) : "v"(p));
}
// Wait all outstanding vmem, then fence the scheduler so the tag checks
// cannot be hoisted above the wait (rule #18: hipcc reorders register-only
// consumers past inline-asm waitcnt despite the "memory" clobber).
__device__ __forceinline__ void vmwait0() {
  asm volatile("s_waitcnt vmcnt(0)" ::: "memory");
  __builtin_amdgcn_sched_barrier(0);
}
__device__ __forceinline__ void mstore(u32* p, u32 v) {
  asm volatile("global_store_dword %0, %1, off sc0 sc1" :: "v"(p), "v"(v)
               : "memory");
}

__device__ __forceinline__ float dot2acc(u32 a, u32 b, float acc) {
#if __has_builtin(__builtin_amdgcn_fdot2)
  return __builtin_amdgcn_fdot2(__builtin_bit_cast(half2_t, a),
                                __builtin_bit_cast(half2_t, b), acc, false);
#else
  half2_t ha = __builtin_bit_cast(half2_t, a);
  half2_t hb = __builtin_bit_cast(half2_t, b);
  return acc + (float)ha[0] * (float)hb[0] + (float)ha[1] * (float)hb[1];
#endif
}
__device__ __forceinline__ float dotq(v4u a, v4u b, float acc) {
  acc = dot2acc(a.x, b.x, acc);
  acc = dot2acc(a.y, b.y, acc);
  acc = dot2acc(a.z, b.z, acc);
  acc = dot2acc(a.w, b.w, acc);
  return acc;
}
__device__ __forceinline__ u32 pkf16(float a, float b) {
#if __has_builtin(__builtin_amdgcn_cvt_pkrtz)
  return __builtin_bit_cast(u32, __builtin_amdgcn_cvt_pkrtz(a, b));
#else
  half2_t h; h[0] = (_Float16)a; h[1] = (_Float16)b;
  return __builtin_bit_cast(u32, h);
#endif
}

// tagged-word helpers -------------------------------------------------------
__device__ __forceinline__ u32 pairw(u32 lo, u32 hi) {
  return (lo & 0xffffu) | (hi << 16);
}
// two v4u of tagged singles (8 consecutive cols) -> one v4u of f16 pairs
__device__ __forceinline__ v4u packpairs(v4u a, v4u b) {
  v4u r;
  r.x = pairw(a.x, a.y); r.y = pairw(a.z, a.w);
  r.z = pairw(b.x, b.y); r.w = pairw(b.z, b.w);
  return r;
}
// OR of (word ^ genw); caller masks 0xffff0000 (low 16 = payload noise)
__device__ __forceinline__ u32 tagx(v4u w, u32 genw) {
  return (w.x ^ genw) | (w.y ^ genw) | (w.z ^ genw) | (w.w ^ genw);
}

// In-register shuffle reduction trees (value for index lane&(M-1)).
template<int M> struct TreeC {
  static __device__ __forceinline__ void run(float* a, int lane, int d) {
    const bool hi = (lane & d) != 0;
#pragma unroll
    for (int i = 0; i < M / 2; ++i) {
      float mine  = hi ? a[2 * i + 1] : a[2 * i];
      float yours = hi ? a[2 * i]     : a[2 * i + 1];
      a[i] = mine + __shfl_xor(yours, d, 64);
    }
    TreeC<M / 2>::run(a, lane, d << 1);
  }
};
template<> struct TreeC<1> {
  static __device__ __forceinline__ void run(float*, int, int) {}
};
template<int M>
__device__ __forceinline__ float tree_reduce(float* a, int lane) {
  TreeC<M>::run(a, lane, 1);
  float v = a[0];
#pragma unroll
  for (int d = M; d <= 32; d <<= 1) v += __shfl_xor(v, d, 64);
  return v;
}

// ---------------------------------------------------------------------------
// RMSNorm: one 256-thread WG per row of 512.
// ---------------------------------------------------------------------------
__global__ __launch_bounds__(256)
void rmsnorm_kernel(const float* __restrict__ x, const float* __restrict__ w,
                    float* __restrict__ y)
{
  __shared__ float redl[256];
  const long row = blockIdx.x;
  const int t = threadIdx.x;
  const float* xr = x + row * DD;
  float v0 = xr[t], v1 = xr[t + 256];
  redl[t] = v0 * v0 + v1 * v1;
  __syncthreads();
  for (int off = 128; off > 0; off >>= 1) {
    if (t < off) redl[t] += redl[t + off];
    __syncthreads();
  }
  float scale = rsqrtf(redl[0] * (1.0f / 512.0f) + 1e-5f);
  float* yr = y + row * DD;
  yr[t]       = v0 * scale * w[t];
  yr[t + 256] = v1 * scale * w[t + 256];
}

// ---------------------------------------------------------------------------
// fp32 tiled GEMM: C[M,N] = A[M,K] @ B[K,N] (+ bias[n]), all row-major.
// ---------------------------------------------------------------------------
__global__ __launch_bounds__(256)
void gemm_fp32(const float* __restrict__ A, const float* __restrict__ B,
               const float* __restrict__ bias, float* __restrict__ C,
               int M, int N, int K)
{
  __shared__ float As[16][68];
  __shared__ float Bs[16][64];
  const int t  = threadIdx.x;
  const int tx = t & 15, ty = t >> 4;
  const long m0 = (long)blockIdx.x * 64;
  const long n0 = (long)blockIdx.y * 64;
  const int ar = t >> 2, ac = (t & 3) * 4;
  const int bk = t >> 4, bn = (t & 15) * 4;
  float acc[4][4] = {{0.f}};

  for (int k0 = 0; k0 < K; k0 += 16) {
    float4 av = *(const float4*)(A + (m0 + ar) * K + k0 + ac);
    float4 bv = *(const float4*)(B + (long)(k0 + bk) * N + n0 + bn);
    As[ac + 0][ar] = av.x; As[ac + 1][ar] = av.y;
    As[ac + 2][ar] = av.z; As[ac + 3][ar] = av.w;
    *(float4*)&Bs[bk][bn] = bv;
    __syncthreads();
#pragma unroll
    for (int kk = 0; kk < 16; ++kk) {
      float4 a = *(const float4*)&As[kk][ty * 4];
      float4 b = *(const float4*)&Bs[kk][tx * 4];
      acc[0][0] = fmaf(a.x, b.x, acc[0][0]); acc[0][1] = fmaf(a.x, b.y, acc[0][1]);
      acc[0][2] = fmaf(a.x, b.z, acc[0][2]); acc[0][3] = fmaf(a.x, b.w, acc[0][3]);
      acc[1][0] = fmaf(a.y, b.x, acc[1][0]); acc[1][1] = fmaf(a.y, b.y, acc[1][1]);
      acc[1][2] = fmaf(a.y, b.z, acc[1][2]); acc[1][3] = fmaf(a.y, b.w, acc[1][3]);
      acc[2][0] = fmaf(a.z, b.x, acc[2][0]); acc[2][1] = fmaf(a.z, b.y, acc[2][1]);
      acc[2][2] = fmaf(a.z, b.z, acc[2][2]); acc[2][3] = fmaf(a.z, b.w, acc[2][3]);
      acc[3][0] = fmaf(a.w, b.x, acc[3][0]); acc[3][1] = fmaf(a.w, b.y, acc[3][1]);
      acc[3][2] = fmaf(a.w, b.z, acc[3][2]); acc[3][3] = fmaf(a.w, b.w, acc[3][3]);
    }
    __syncthreads();
  }
  float4 bb = make_float4(0.f, 0.f, 0.f, 0.f);
  if (bias) bb = *(const float4*)(bias + n0 + tx * 4);
#pragma unroll
  for (int i = 0; i < 4; ++i) {
    float4 o;
    o.x = acc[i][0] + bb.x; o.y = acc[i][1] + bb.y;
    o.z = acc[i][2] + bb.z; o.w = acc[i][3] + bb.w;
    *(float4*)(C + (m0 + ty * 4 + i) * N + n0 + tx * 4) = o;
  }
}

// ---------------------------------------------------------------------------
// Persistent scan: 512 WGs x 256 thr, 64 KB static LDS (f16 weight pairs).
// Tagged arrays (u32 = gen<<16 | f16):
//   tc[32][512]   c values  (written S3 tag it+1, read S1 tag it)
//   ti[32][512]   innov     (written S1 tag it+1, read S2 tag it+1)
//   tkk[32][1536] kmid      (written S2 tag it+1, read S3 tag it+1)
// ---------------------------------------------------------------------------
__global__ __launch_bounds__(256, 2)
void scan_kernel(const float* __restrict__ gx,
                 const float* __restrict__ Whh, const float* __restrict__ bhh,
                 const float* __restrict__ loglam,
                 const float* __restrict__ kW1, const float* __restrict__ kb1,
                 const float* __restrict__ kW2, const float* __restrict__ kb2,
                 u32* __restrict__ tc, u32* __restrict__ ti,
                 u32* __restrict__ tkk, float* __restrict__ hs)
{
  const int blk  = blockIdx.x;
  const int g    = blk & 7;         // group (rows 4g..4g+3)
  const int s    = blk >> 3;        // slot 0..63
  const int tid  = threadIdx.x;
  const int q    = tid >> 6;        // wave 0..3
  const int lane = tid & 63;
  const int jz   = s * 8;
  const int jm   = s * 24;

  __shared__ u32 wh[16 * 256];      // 16 KB: 8 z-cols + 8 m-cols, f16 pairs
  __shared__ u32 w1s[24 * 256];     // 24 KB
  __shared__ u32 w2s[8 * 768];      // 24 KB  (total 64 KB)

  // ---- one-time weight staging (fp32 -> f16 pairs; pair p <-> k=2p,2p+1) ----
  for (int idx = tid; idx < 16 * 256; idx += 256) {
    int c = idx >> 8, p = idx & 255;
    int gcol = (c < 8) ? (jz + c) : (512 + jz + (c - 8));
    wh[idx] = pkf16(Whh[(size_t)(2 * p) * G2H + gcol],
                    Whh[(size_t)(2 * p + 1) * G2H + gcol]);
  }
  for (int idx = tid; idx < 24 * 256; idx += 256) {
    int c = idx >> 8, p = idx & 255;
    w1s[idx] = pkf16(kW1[(size_t)(2 * p) * K3H + jm + c],
                     kW1[(size_t)(2 * p + 1) * K3H + jm + c]);
  }
  for (int idx = tid; idx < 8 * 768; idx += 256) {
    int c = idx / 768, p = idx - c * 768;
    w2s[idx] = pkf16(kW2[(size_t)(2 * p) * HH + jz + c],
                     kW2[(size_t)(2 * p + 1) * HH + jz + c]);
  }
  __syncthreads();   // weights visible; waves free-run from here on

  // per-lane constants (state mapping: r=(lane>>1)&3, ci=lane&1, lanes<8)
  const int colA = jz + 2 * q + (lane & 1);
  const float Ab   = 1.f - expf(loglam[colA]);
  const float bz   = bhh[colA];
  const float bm   = bhh[512 + colA];
  const float kb2c = kb2[colA];
  int kb1i = lane & 7; if (kb1i > 5) kb1i = 5;
  const float kb1v = kb1[jm + 6 * q + kb1i];

  const int r_st  = (lane >> 1) & 3;
  const int growst = 4 * g + r_st;
  const size_t hsoff = (size_t)growst * LSEQ * HH + colA;
  const size_t gxoff = (size_t)growst * LSEQ * G2H + colA;

  // tagged-row pointers (each lane covers cols 8*lane..8*lane+7 per chunk)
  const u32* tcl[4]; const u32* til[4]; const u32* tkl[4];
#pragma unroll
  for (int r = 0; r < 4; ++r) {
    tcl[r] = tc  + (size_t)(4 * g + r) * 512  + lane * 8;
    til[r] = ti  + (size_t)(4 * g + r) * 512  + lane * 8;
    tkl[r] = tkk + (size_t)(4 * g + r) * 1536 + lane * 8;
  }
  u32* tiw = ti + (size_t)growst * 512 + colA;      // lanes<8
  u32* tcw = tc + (size_t)growst * 512 + colA;      // lanes<8
  const int rr = (lane >> 3) & 3, cc = lane & 7;    // S2 store map (lanes<32)
  u32* tkw = tkk + (size_t)(4 * g + rr) * 1536 + jm + 6 * q + cc;

  float A_own = 0.f, c_own = 0.f, M_own = 0.f, I_own = 0.f, s_own = 1.f;
  int spin = 1 << 22;   // hang guard: wave-uniform global poll budget

  for (int it = 0; it <= LSEQ; ++it) {
    const u32 genc = ((u32)it) << 16;
    const u32 genn = ((u32)(it + 1)) << 16;

    // gx prefetch (cached, read-once) — overlaps the S1 poll
    float gxz = 0.f, gxm = 0.f;
    if (lane < 8 && it < LSEQ) {
      gxz = gx[gxoff + (size_t)it * G2H];
      gxm = gx[gxoff + (size_t)it * G2H + 512];
    }

    // ---- S1: poll c(it) per row ; sumsq -> s ; g = h@W_hh ; innov ----
    v4u cv[4];
#pragma unroll
    for (int r = 0; r < 4; ++r) {
      v4u w0, w1;
      for (;;) {
        mload4(w0, tcl[r]); mload4(w1, tcl[r] + 4);
        vmwait0();
        u32 d = tagx(w0, genc) | tagx(w1, genc);
        if (__all((d & 0xffff0000u) == 0)) break;
        if (--spin < 0) break;
      }
      cv[r] = packpairs(w0, w1);
    }

    float a4[4] = { dotq(cv[0], cv[0], 0.f), dotq(cv[1], cv[1], 0.f),
                    dotq(cv[2], cv[2], 0.f), dotq(cv[3], cv[3], 0.f) };
    float a16[16];
#pragma unroll
    for (int t = 0; t < 4; ++t) {          // t<2: z col 2q+t ; t>=2: m col
      int col = (t < 2) ? (2 * q + t) : (8 + 2 * q + (t - 2));
      v4u wq = *(const v4u*)(wh + col * 256 + lane * 4);
      a16[0 * 4 + t] = dotq(cv[0], wq, 0.f);
      a16[1 * 4 + t] = dotq(cv[1], wq, 0.f);
      a16[2 * 4 + t] = dotq(cv[2], wq, 0.f);
      a16[3 * 4 + t] = dotq(cv[3], wq, 0.f);
    }
    float ssv = tree_reduce<4>(a4, lane);     // row = lane&3
    float g16 = tree_reduce<16>(a16, lane);   // (r=(lane&15)>>2, t=lane&3)
    float sq  = __shfl(ssv, r_st, 64);
    float s_loc = fminf(1.f, 10.f * rsqrtf(sq + 1e-6f));
    float gz = __shfl(g16, (r_st * 4 + (lane & 1)) & 63, 64);
    float gm = __shfl(g16, (r_st * 4 + 2 + (lane & 1)) & 63, 64);
    if (lane < 8 && it >= 1)
      hs[hsoff + (size_t)(it - 1) * HH] = s_loc * c_own;
    if (it == LSEQ) break;
    float gzv = gz * s_loc + gxz + bz;
    float gmv = gm * s_loc + gxm + bm;
    float Mv = tanhf(gmv);
    float ivf = gzv - A_own * (s_loc * c_own) - Mv;
    if (lane < 8) {
      M_own = Mv; I_own = ivf; s_own = s_loc;
      mstore(tiw, genn | pkf16(ivf, 0.f));
    }

    // ---- S2: poll innov(it+1) per row ; kmid = gelu(innov @ kW1 + kb1) ----
    v4u pv[4];
#pragma unroll
    for (int r = 0; r < 4; ++r) {
      v4u w0, w1;
      for (;;) {
        mload4(w0, til[r]); mload4(w1, til[r] + 4);
        vmwait0();
        u32 d = tagx(w0, genn) | tagx(w1, genn);
        if (__all((d & 0xffff0000u) == 0)) break;
        if (--spin < 0) break;
      }
      pv[r] = packpairs(w0, w1);
    }

    float a32[32];
#pragma unroll
    for (int i = 0; i < 32; ++i) a32[i] = 0.f;
#pragma unroll
    for (int cj = 0; cj < 6; ++cj) {
      v4u wq = *(const v4u*)(w1s + (6 * q + cj) * 256 + lane * 4);
      a32[0 * 8 + cj] = dotq(pv[0], wq, 0.f);
      a32[1 * 8 + cj] = dotq(pv[1], wq, 0.f);
      a32[2 * 8 + cj] = dotq(pv[2], wq, 0.f);
      a32[3 * 8 + cj] = dotq(pv[3], wq, 0.f);
    }
    float t32 = tree_reduce<32>(a32, lane);   // (r=(lane&31)>>3, cc=lane&7)
    float kvb = t32 + kb1v;
    float gl = 0.5f * kvb * (1.f + erff(kvb * 0.7071067811865476f));
    if (lane < 32 && cc < 6)
      mstore(tkw, genn | pkf16(gl, 0.f));

    // ---- S3: poll kmid(it+1) per row ; K = tanh(kmid@kW2 + kb2)*0.5 ; c ----
    v4u kp[4][3];
#pragma unroll
    for (int r = 0; r < 4; ++r) {
      v4u w0, w1, w2, w3, w4, w5;
      for (;;) {
        mload4(w0, tkl[r]);        mload4(w1, tkl[r] + 4);
        mload4(w2, tkl[r] + 512);  mload4(w3, tkl[r] + 516);
        mload4(w4, tkl[r] + 1024); mload4(w5, tkl[r] + 1028);
        vmwait0();
        u32 d = tagx(w0, genn) | tagx(w1, genn) | tagx(w2, genn) |
                tagx(w3, genn) | tagx(w4, genn) | tagx(w5, genn);
        if (__all((d & 0xffff0000u) == 0)) break;
        if (--spin < 0) break;
      }
      kp[r][0] = packpairs(w0, w1);
      kp[r][1] = packpairs(w2, w3);
      kp[r][2] = packpairs(w4, w5);
    }

    float a8[8];
#pragma unroll
    for (int ci = 0; ci < 2; ++ci) {
      const u32* wc = w2s + (2 * q + ci) * 768 + lane * 4;
      v4u wq0 = *(const v4u*)(wc);
      v4u wq1 = *(const v4u*)(wc + 256);
      v4u wq2 = *(const v4u*)(wc + 512);
#pragma unroll
      for (int r = 0; r < 4; ++r)
        a8[r * 2 + ci] = dotq(kp[r][2], wq2,
                         dotq(kp[r][1], wq1, dotq(kp[r][0], wq0, 0.f)));
    }
    float krd = tree_reduce<8>(a8, lane);   // (r=(lane&7)>>1, ci=lane&1)
    float Kv = tanhf(krd + kb2c) * 0.5f;
    float An = Ab * (1.f - Kv * Kv);
    float cn = An * (s_own * c_own) + Kv * I_own + M_own;
    if (lane < 8) {
      A_own = An; c_own = cn;
      mstore(tcw, genn | pkf16(cn, 0.f));
    }
  }
}

// ---------------------------------------------------------------------------
// Workspace layout (bytes):
//   [0, 32M)    xn (reused as hs)
//   [32M, 96M)  gx
//   [96M,128M)  xmid
//   [128M, ..)  tc 64K | ti 64K | tkk 192K   (tagged comm arrays)
// ---------------------------------------------------------------------------
extern "C" void kernel_launch(void* const* d_in, const int* in_sizes, int n_in,
                              void* d_out, int out_size, void* d_ws, size_t ws_size,
                              hipStream_t stream) {
  const float* x      = (const float*)d_in[0];
  const float* norm_w = (const float*)d_in[1];
  const float* W_ih   = (const float*)d_in[2];
  const float* b_ih   = (const float*)d_in[3];
  const float* W_hh   = (const float*)d_in[4];
  const float* b_hh   = (const float*)d_in[5];
  const float* loglam = (const float*)d_in[6];
  const float* kW1    = (const float*)d_in[7];
  const float* kb1    = (const float*)d_in[8];
  const float* kW2    = (const float*)d_in[9];
  const float* kb2    = (const float*)d_in[10];
  const float* Wo     = (const float*)d_in[11];
  float* out = (float*)d_out;

  char* ws = (char*)d_ws;
  float* xn   = (float*)(ws);
  float* gxb  = (float*)(ws + (size_t)33554432);
  float* xmid = (float*)(ws + (size_t)100663296);
  u32* tc  = (u32*)(ws + (size_t)134217728);
  u32* ti  = tc + 16384;          // 32*512
  u32* tkk = ti + 16384;          // 32*1536
  float* hs = xn;

  const size_t tag_bytes = (size_t)(16384 + 16384 + 49152) * sizeof(u32);

  for (int l = 0; l < 2; ++l) {
    const float* xin = l ? (const float*)xmid : x;
    float* cout = l ? out : xmid;

    rmsnorm_kernel<<<BB * LSEQ, 256, 0, stream>>>(xin, norm_w, xn);

    gemm_fp32<<<dim3(256, 16), 256, 0, stream>>>(
        xn, W_ih + (size_t)l * DD * G2H, b_ih + (size_t)l * G2H, gxb,
        BB * LSEQ, G2H, DD);

    // reset tags to generation 0 (== initial c state of 0.0h, tag 0)
    hipMemsetAsync(tc, 0, tag_bytes, stream);

    scan_kernel<<<NG * GWG, 256, 0, stream>>>(
        gxb,
        W_hh + (size_t)l * HH * G2H, b_hh + (size_t)l * G2H,
        loglam + (size_t)l * HH,
        kW1 + (size_t)l * HH * K3H, kb1 + (size_t)l * K3H,
        kW2 + (size_t)l * K3H * HH, kb2 + (size_t)l * HH,
        tc, ti, tkk, hs);

    gemm_fp32<<<dim3(256, 8), 256, 0, stream>>>(
        hs, Wo + (size_t)l * HH * DD, nullptr, cout,
        BB * LSEQ, DD, HH);
  }
}

// Round 3
// 28644.681 us; speedup vs baseline: 1.4952x; 1.4952x over previous
//
#include <hip/hip_runtime.h>
#include <math.h>

// Problem constants (match reference)
#define BB   32
#define LSEQ 512
#define DD   512
#define HH   512
#define G2H  1024
#define K3H  1536

// Scan: 8 groups x 64 WGs. Group g owns batch rows 4g..4g+3. WG slot s owns
// c/innov/K cols jz=8s..8s+7 and kmid cols jm=24s..24s+23. WG = 256 thr =
// 4 waves; wave q owns col pair (2 c-cols / 6 kmid-cols) x all 4 rows.
//
// R3: 1-hop tagged dataflow (R2-proven protocol) + SLICED polling with LDS
// broadcast. Rationale: old barrier kernel ran at 4.0 TB/s of sc1 gather
// traffic (40 MB/step / 10 us) == bandwidth-bound; R2 re-swept 4x-redundant
// tagged regions continuously (congestion + serial per-row polls) -> 19 ms.
// Here wave q polls ONLY batch-row q of each tagged region in ONE batched
// sweep, shares the packed payload via a 12 KB LDS buffer, and all waves
// read rows 0..3 from LDS. Gather volume: 20 MB/step (2x below old best).
//
// Tagged word: u32 = (gen<<16) | f16bits(value). Dword atomicity only.
// Overwrite safety (2 phases of slack): producer stores phase p+3 only after
// its WG's syncthreads proved all 4 waves completed phase-p loads; the
// transitive chain across slots covers the group (see R2 derivation).
// CO-RESIDENCY required: LDS 76KB -> 2 WG/CU; all 512 WGs resident.
// HANG GUARD: spin budget; exhaustion exits the poll loop only (phase
// structure and syncthreads counts preserved) -> fast garbage fail, no hang.
#define NG   8
#define GWG  64

typedef unsigned int u32;
typedef _Float16 half2_t __attribute__((ext_vector_type(2)));
typedef u32 v4u __attribute__((ext_vector_type(4)));

// ---- coherence-point memory ops (proven pattern) --------------------------
__device__ __forceinline__ void mload4(v4u& d, const u32* p) {
  asm volatile("global_load_dwordx4 %0, %1, off sc1" : "=v"(d) : "v"(p));
}
// Wait all outstanding vmem, then fence the scheduler so tag checks can't be
// hoisted above the wait (rule #18).
__device__ __forceinline__ void vmwait0() {
  asm volatile("s_waitcnt vmcnt(0)" ::: "memory");
  __builtin_amdgcn_sched_barrier(0);
}
__device__ __forceinline__ void mstore(u32* p, u32 v) {
  asm volatile("global_store_dword %0, %1, off sc0 sc1" :: "v"(p), "v"(v)
               : "memory");
}

__device__ __forceinline__ float dot2acc(u32 a, u32 b, float acc) {
#if __has_builtin(__builtin_amdgcn_fdot2)
  return __builtin_amdgcn_fdot2(__builtin_bit_cast(half2_t, a),
                                __builtin_bit_cast(half2_t, b), acc, false);
#else
  half2_t ha = __builtin_bit_cast(half2_t, a);
  half2_t hb = __builtin_bit_cast(half2_t, b);
  return acc + (float)ha[0] * (float)hb[0] + (float)ha[1] * (float)hb[1];
#endif
}
__device__ __forceinline__ float dotq(v4u a, v4u b, float acc) {
  acc = dot2acc(a.x, b.x, acc);
  acc = dot2acc(a.y, b.y, acc);
  acc = dot2acc(a.z, b.z, acc);
  acc = dot2acc(a.w, b.w, acc);
  return acc;
}
__device__ __forceinline__ u32 pkf16(float a, float b) {
#if __has_builtin(__builtin_amdgcn_cvt_pkrtz)
  return __builtin_bit_cast(u32, __builtin_amdgcn_cvt_pkrtz(a, b));
#else
  half2_t h; h[0] = (_Float16)a; h[1] = (_Float16)b;
  return __builtin_bit_cast(u32, h);
#endif
}

// tagged-word helpers -------------------------------------------------------
__device__ __forceinline__ u32 pairw(u32 lo, u32 hi) {
  return (lo & 0xffffu) | (hi << 16);
}
// two v4u of tagged singles (8 consecutive cols) -> one v4u of f16 pairs
__device__ __forceinline__ v4u packpairs(v4u a, v4u b) {
  v4u r;
  r.x = pairw(a.x, a.y); r.y = pairw(a.z, a.w);
  r.z = pairw(b.x, b.y); r.w = pairw(b.z, b.w);
  return r;
}
// OR of (word ^ genw); caller masks 0xffff0000 (low 16 = payload noise)
__device__ __forceinline__ u32 tagx(v4u w, u32 genw) {
  return (w.x ^ genw) | (w.y ^ genw) | (w.z ^ genw) | (w.w ^ genw);
}

// In-register shuffle reduction trees (value for index lane&(M-1)).
template<int M> struct TreeC {
  static __device__ __forceinline__ void run(float* a, int lane, int d) {
    const bool hi = (lane & d) != 0;
#pragma unroll
    for (int i = 0; i < M / 2; ++i) {
      float mine  = hi ? a[2 * i + 1] : a[2 * i];
      float yours = hi ? a[2 * i]     : a[2 * i + 1];
      a[i] = mine + __shfl_xor(yours, d, 64);
    }
    TreeC<M / 2>::run(a, lane, d << 1);
  }
};
template<> struct TreeC<1> {
  static __device__ __forceinline__ void run(float*, int, int) {}
};
template<int M>
__device__ __forceinline__ float tree_reduce(float* a, int lane) {
  TreeC<M>::run(a, lane, 1);
  float v = a[0];
#pragma unroll
  for (int d = M; d <= 32; d <<= 1) v += __shfl_xor(v, d, 64);
  return v;
}

// ---------------------------------------------------------------------------
// RMSNorm: one 256-thread WG per row of 512.
// ---------------------------------------------------------------------------
__global__ __launch_bounds__(256)
void rmsnorm_kernel(const float* __restrict__ x, const float* __restrict__ w,
                    float* __restrict__ y)
{
  __shared__ float redl[256];
  const long row = blockIdx.x;
  const int t = threadIdx.x;
  const float* xr = x + row * DD;
  float v0 = xr[t], v1 = xr[t + 256];
  redl[t] = v0 * v0 + v1 * v1;
  __syncthreads();
  for (int off = 128; off > 0; off >>= 1) {
    if (t < off) redl[t] += redl[t + off];
    __syncthreads();
  }
  float scale = rsqrtf(redl[0] * (1.0f / 512.0f) + 1e-5f);
  float* yr = y + row * DD;
  yr[t]       = v0 * scale * w[t];
  yr[t + 256] = v1 * scale * w[t + 256];
}

// ---------------------------------------------------------------------------
// fp32 tiled GEMM: C[M,N] = A[M,K] @ B[K,N] (+ bias[n]), all row-major.
// ---------------------------------------------------------------------------
__global__ __launch_bounds__(256)
void gemm_fp32(const float* __restrict__ A, const float* __restrict__ B,
               const float* __restrict__ bias, float* __restrict__ C,
               int M, int N, int K)
{
  __shared__ float As[16][68];
  __shared__ float Bs[16][64];
  const int t  = threadIdx.x;
  const int tx = t & 15, ty = t >> 4;
  const long m0 = (long)blockIdx.x * 64;
  const long n0 = (long)blockIdx.y * 64;
  const int ar = t >> 2, ac = (t & 3) * 4;
  const int bk = t >> 4, bn = (t & 15) * 4;
  float acc[4][4] = {{0.f}};

  for (int k0 = 0; k0 < K; k0 += 16) {
    float4 av = *(const float4*)(A + (m0 + ar) * K + k0 + ac);
    float4 bv = *(const float4*)(B + (long)(k0 + bk) * N + n0 + bn);
    As[ac + 0][ar] = av.x; As[ac + 1][ar] = av.y;
    As[ac + 2][ar] = av.z; As[ac + 3][ar] = av.w;
    *(float4*)&Bs[bk][bn] = bv;
    __syncthreads();
#pragma unroll
    for (int kk = 0; kk < 16; ++kk) {
      float4 a = *(const float4*)&As[kk][ty * 4];
      float4 b = *(const float4*)&Bs[kk][tx * 4];
      acc[0][0] = fmaf(a.x, b.x, acc[0][0]); acc[0][1] = fmaf(a.x, b.y, acc[0][1]);
      acc[0][2] = fmaf(a.x, b.z, acc[0][2]); acc[0][3] = fmaf(a.x, b.w, acc[0][3]);
      acc[1][0] = fmaf(a.y, b.x, acc[1][0]); acc[1][1] = fmaf(a.y, b.y, acc[1][1]);
      acc[1][2] = fmaf(a.y, b.z, acc[1][2]); acc[1][3] = fmaf(a.y, b.w, acc[1][3]);
      acc[2][0] = fmaf(a.z, b.x, acc[2][0]); acc[2][1] = fmaf(a.z, b.y, acc[2][1]);
      acc[2][2] = fmaf(a.z, b.z, acc[2][2]); acc[2][3] = fmaf(a.z, b.w, acc[2][3]);
      acc[3][0] = fmaf(a.w, b.x, acc[3][0]); acc[3][1] = fmaf(a.w, b.y, acc[3][1]);
      acc[3][2] = fmaf(a.w, b.z, acc[3][2]); acc[3][3] = fmaf(a.w, b.w, acc[3][3]);
    }
    __syncthreads();
  }
  float4 bb = make_float4(0.f, 0.f, 0.f, 0.f);
  if (bias) bb = *(const float4*)(bias + n0 + tx * 4);
#pragma unroll
  for (int i = 0; i < 4; ++i) {
    float4 o;
    o.x = acc[i][0] + bb.x; o.y = acc[i][1] + bb.y;
    o.z = acc[i][2] + bb.z; o.w = acc[i][3] + bb.w;
    *(float4*)(C + (m0 + ty * 4 + i) * N + n0 + tx * 4) = o;
  }
}

// ---------------------------------------------------------------------------
// Persistent scan: 512 WGs x 256 thr, 76 KB static LDS.
// Tagged arrays (u32 = gen<<16 | f16):
//   tc[32][512]   c values  (written S3 tag it+1, read S1 tag it)
//   ti[32][512]   innov     (written S1 tag it+1, read S2 tag it+1)
//   tkk[32][1536] kmid      (written S2 tag it+1, read S3 tag it+1)
// Wave q polls row (4g+q) only; payload broadcast via LDS bc[].
// ---------------------------------------------------------------------------
__global__ __launch_bounds__(256, 2)
void scan_kernel(const float* __restrict__ gx,
                 const float* __restrict__ Whh, const float* __restrict__ bhh,
                 const float* __restrict__ loglam,
                 const float* __restrict__ kW1, const float* __restrict__ kb1,
                 const float* __restrict__ kW2, const float* __restrict__ kb2,
                 u32* __restrict__ tc, u32* __restrict__ ti,
                 u32* __restrict__ tkk, float* __restrict__ hs)
{
  const int blk  = blockIdx.x;
  const int g    = blk & 7;         // group (rows 4g..4g+3)
  const int s    = blk >> 3;        // slot 0..63
  const int tid  = threadIdx.x;
  const int q    = tid >> 6;        // wave 0..3
  const int lane = tid & 63;
  const int jz   = s * 8;
  const int jm   = s * 24;

  __shared__ u32 wh[16 * 256];      // 16 KB: 8 z-cols + 8 m-cols, f16 pairs
  __shared__ u32 w1s[24 * 256];     // 24 KB
  __shared__ u32 w2s[8 * 768];      // 24 KB
  __shared__ u32 bc[4 * 768];       // 12 KB broadcast buffer (total 76 KB)

  // ---- one-time weight staging (fp32 -> f16 pairs; pair p <-> k=2p,2p+1) ----
  for (int idx = tid; idx < 16 * 256; idx += 256) {
    int c = idx >> 8, p = idx & 255;
    int gcol = (c < 8) ? (jz + c) : (512 + jz + (c - 8));
    wh[idx] = pkf16(Whh[(size_t)(2 * p) * G2H + gcol],
                    Whh[(size_t)(2 * p + 1) * G2H + gcol]);
  }
  for (int idx = tid; idx < 24 * 256; idx += 256) {
    int c = idx >> 8, p = idx & 255;
    w1s[idx] = pkf16(kW1[(size_t)(2 * p) * K3H + jm + c],
                     kW1[(size_t)(2 * p + 1) * K3H + jm + c]);
  }
  for (int idx = tid; idx < 8 * 768; idx += 256) {
    int c = idx / 768, p = idx - c * 768;
    w2s[idx] = pkf16(kW2[(size_t)(2 * p) * HH + jz + c],
                     kW2[(size_t)(2 * p + 1) * HH + jz + c]);
  }
  __syncthreads();   // weights visible

  // per-lane constants (state mapping: r=(lane>>1)&3, ci=lane&1, lanes<8)
  const int colA = jz + 2 * q + (lane & 1);
  const float Ab   = 1.f - expf(loglam[colA]);
  const float bz   = bhh[colA];
  const float bm   = bhh[512 + colA];
  const float kb2c = kb2[colA];
  int kb1i = lane & 7; if (kb1i > 5) kb1i = 5;
  const float kb1v = kb1[jm + 6 * q + kb1i];

  const int r_st  = (lane >> 1) & 3;
  const int growst = 4 * g + r_st;
  const size_t hsoff = (size_t)growst * LSEQ * HH + colA;
  const size_t gxoff = (size_t)growst * LSEQ * G2H + colA;

  // slice pointers: wave q polls batch-row 4g+q, lane covers cols 8L..8L+7
  const u32* tcs = tc  + (size_t)(4 * g + q) * 512  + lane * 8;
  const u32* tis = ti  + (size_t)(4 * g + q) * 512  + lane * 8;
  const u32* tks = tkk + (size_t)(4 * g + q) * 1536 + lane * 8;

  u32* tiw = ti + (size_t)growst * 512 + colA;      // lanes<8
  u32* tcw = tc + (size_t)growst * 512 + colA;      // lanes<8
  const int rr = (lane >> 3) & 3, cc = lane & 7;    // S2 store map (lanes<32)
  u32* tkw = tkk + (size_t)(4 * g + rr) * 1536 + jm + 6 * q + cc;

  float A_own = 0.f, c_own = 0.f, M_own = 0.f, I_own = 0.f, s_own = 1.f;
  int spin = 1 << 22;   // hang guard: wave-uniform poll budget

  for (int it = 0; it <= LSEQ; ++it) {
    const u32 genc = ((u32)it) << 16;
    const u32 genn = ((u32)(it + 1)) << 16;

    // gx prefetch (cached, read-once) — completes under the S1 poll's waits
    float gxz = 0.f, gxm = 0.f;
    if (lane < 8 && it < LSEQ) {
      gxz = gx[gxoff + (size_t)it * G2H];
      gxm = gx[gxoff + (size_t)it * G2H + 512];
    }

    // ---- S1: wave q polls c(it) row q (one batched sweep) -----------------
    {
      v4u w0, w1;
      for (;;) {
        mload4(w0, tcs); mload4(w1, tcs + 4);
        vmwait0();
        u32 d = tagx(w0, genc) | tagx(w1, genc);
        if (__all((d & 0xffff0000u) == 0)) break;
        if (--spin < 0) break;
      }
      *(v4u*)(bc + q * 256 + lane * 4) = packpairs(w0, w1);
    }
    __syncthreads();                      // payload ready in LDS
    v4u cv[4];
#pragma unroll
    for (int r = 0; r < 4; ++r) cv[r] = *(const v4u*)(bc + r * 256 + lane * 4);

    float a4[4] = { dotq(cv[0], cv[0], 0.f), dotq(cv[1], cv[1], 0.f),
                    dotq(cv[2], cv[2], 0.f), dotq(cv[3], cv[3], 0.f) };
    float a16[16];
#pragma unroll
    for (int t = 0; t < 4; ++t) {          // t<2: z col 2q+t ; t>=2: m col
      int col = (t < 2) ? (2 * q + t) : (8 + 2 * q + (t - 2));
      v4u wq = *(const v4u*)(wh + col * 256 + lane * 4);
      a16[0 * 4 + t] = dotq(cv[0], wq, 0.f);
      a16[1 * 4 + t] = dotq(cv[1], wq, 0.f);
      a16[2 * 4 + t] = dotq(cv[2], wq, 0.f);
      a16[3 * 4 + t] = dotq(cv[3], wq, 0.f);
    }
    float ssv = tree_reduce<4>(a4, lane);     // row = lane&3
    float g16 = tree_reduce<16>(a16, lane);   // (r=(lane&15)>>2, t=lane&3)
    float sq  = __shfl(ssv, r_st, 64);
    float s_loc = fminf(1.f, 10.f * rsqrtf(sq + 1e-6f));
    float gz = __shfl(g16, (r_st * 4 + (lane & 1)) & 63, 64);
    float gm = __shfl(g16, (r_st * 4 + 2 + (lane & 1)) & 63, 64);
    if (lane < 8 && it >= 1)
      hs[hsoff + (size_t)(it - 1) * HH] = s_loc * c_own;
    if (it == LSEQ) break;                // uniform across all waves/WGs
    float gzv = gz * s_loc + gxz + bz;
    float gmv = gm * s_loc + gxm + bm;
    float Mv = tanhf(gmv);
    float ivf = gzv - A_own * (s_loc * c_own) - Mv;
    if (lane < 8) {
      M_own = Mv; I_own = ivf; s_own = s_loc;
      mstore(tiw, genn | pkf16(ivf, 0.f));
    }
    __syncthreads();                      // all waves done reading bc (S1)

    // ---- S2: wave q polls innov(it+1) row q ------------------------------
    {
      v4u w0, w1;
      for (;;) {
        mload4(w0, tis); mload4(w1, tis + 4);
        vmwait0();
        u32 d = tagx(w0, genn) | tagx(w1, genn);
        if (__all((d & 0xffff0000u) == 0)) break;
        if (--spin < 0) break;
      }
      *(v4u*)(bc + q * 256 + lane * 4) = packpairs(w0, w1);
    }
    __syncthreads();
    v4u pv[4];
#pragma unroll
    for (int r = 0; r < 4; ++r) pv[r] = *(const v4u*)(bc + r * 256 + lane * 4);

    float a32[32];
#pragma unroll
    for (int i = 0; i < 32; ++i) a32[i] = 0.f;
#pragma unroll
    for (int cj = 0; cj < 6; ++cj) {
      v4u wq = *(const v4u*)(w1s + (6 * q + cj) * 256 + lane * 4);
      a32[0 * 8 + cj] = dotq(pv[0], wq, 0.f);
      a32[1 * 8 + cj] = dotq(pv[1], wq, 0.f);
      a32[2 * 8 + cj] = dotq(pv[2], wq, 0.f);
      a32[3 * 8 + cj] = dotq(pv[3], wq, 0.f);
    }
    float t32 = tree_reduce<32>(a32, lane);   // (r=(lane&31)>>3, cc=lane&7)
    float kvb = t32 + kb1v;
    float gl = 0.5f * kvb * (1.f + erff(kvb * 0.7071067811865476f));
    if (lane < 32 && cc < 6)
      mstore(tkw, genn | pkf16(gl, 0.f));
    __syncthreads();                      // all waves done reading bc (S2)

    // ---- S3: wave q polls kmid(it+1) row q (1536 words, one sweep) -------
    {
      v4u w0, w1, w2, w3, w4, w5;
      for (;;) {
        mload4(w0, tks);        mload4(w1, tks + 4);
        mload4(w2, tks + 512);  mload4(w3, tks + 516);
        mload4(w4, tks + 1024); mload4(w5, tks + 1028);
        vmwait0();
        u32 d = tagx(w0, genn) | tagx(w1, genn) | tagx(w2, genn) |
                tagx(w3, genn) | tagx(w4, genn) | tagx(w5, genn);
        if (__all((d & 0xffff0000u) == 0)) break;
        if (--spin < 0) break;
      }
      *(v4u*)(bc + q * 768 +   0 + lane * 4) = packpairs(w0, w1);
      *(v4u*)(bc + q * 768 + 256 + lane * 4) = packpairs(w2, w3);
      *(v4u*)(bc + q * 768 + 512 + lane * 4) = packpairs(w4, w5);
    }
    __syncthreads();
    float a8[8];
#pragma unroll
    for (int ci = 0; ci < 2; ++ci) {
      const u32* wc = w2s + (2 * q + ci) * 768 + lane * 4;
      v4u wq0 = *(const v4u*)(wc);
      v4u wq1 = *(const v4u*)(wc + 256);
      v4u wq2 = *(const v4u*)(wc + 512);
#pragma unroll
      for (int r = 0; r < 4; ++r) {
        v4u k0 = *(const v4u*)(bc + r * 768 +   0 + lane * 4);
        v4u k1 = *(const v4u*)(bc + r * 768 + 256 + lane * 4);
        v4u k2 = *(const v4u*)(bc + r * 768 + 512 + lane * 4);
        a8[r * 2 + ci] = dotq(k2, wq2, dotq(k1, wq1, dotq(k0, wq0, 0.f)));
      }
    }
    float krd = tree_reduce<8>(a8, lane);   // (r=(lane&7)>>1, ci=lane&1)
    float Kv = tanhf(krd + kb2c) * 0.5f;
    float An = Ab * (1.f - Kv * Kv);
    float cn = An * (s_own * c_own) + Kv * I_own + M_own;
    if (lane < 8) {
      A_own = An; c_own = cn;
      mstore(tcw, genn | pkf16(cn, 0.f));
    }
    __syncthreads();                      // all waves done reading bc (S3)
  }
}

// ---------------------------------------------------------------------------
// Workspace layout (bytes):
//   [0, 32M)    xn (reused as hs)
//   [32M, 96M)  gx
//   [96M,128M)  xmid
//   [128M, ..)  tc 64K | ti 64K | tkk 192K   (tagged comm arrays)
// ---------------------------------------------------------------------------
extern "C" void kernel_launch(void* const* d_in, const int* in_sizes, int n_in,
                              void* d_out, int out_size, void* d_ws, size_t ws_size,
                              hipStream_t stream) {
  const float* x      = (const float*)d_in[0];
  const float* norm_w = (const float*)d_in[1];
  const float* W_ih   = (const float*)d_in[2];
  const float* b_ih   = (const float*)d_in[3];
  const float* W_hh   = (const float*)d_in[4];
  const float* b_hh   = (const float*)d_in[5];
  const float* loglam = (const float*)d_in[6];
  const float* kW1    = (const float*)d_in[7];
  const float* kb1    = (const float*)d_in[8];
  const float* kW2    = (const float*)d_in[9];
  const float* kb2    = (const float*)d_in[10];
  const float* Wo     = (const float*)d_in[11];
  float* out = (float*)d_out;

  char* ws = (char*)d_ws;
  float* xn   = (float*)(ws);
  float* gxb  = (float*)(ws + (size_t)33554432);
  float* xmid = (float*)(ws + (size_t)100663296);
  u32* tc  = (u32*)(ws + (size_t)134217728);
  u32* ti  = tc + 16384;          // 32*512
  u32* tkk = ti + 16384;          // 32*1536
  float* hs = xn;

  const size_t tag_bytes = (size_t)(16384 + 16384 + 49152) * sizeof(u32);

  for (int l = 0; l < 2; ++l) {
    const float* xin = l ? (const float*)xmid : x;
    float* cout = l ? out : xmid;

    rmsnorm_kernel<<<BB * LSEQ, 256, 0, stream>>>(xin, norm_w, xn);

    gemm_fp32<<<dim3(256, 16), 256, 0, stream>>>(
        xn, W_ih + (size_t)l * DD * G2H, b_ih + (size_t)l * G2H, gxb,
        BB * LSEQ, G2H, DD);

    // reset tags to generation 0 (== initial c state of 0.0h, tag 0)
    hipMemsetAsync(tc, 0, tag_bytes, stream);

    scan_kernel<<<NG * GWG, 256, 0, stream>>>(
        gxb,
        W_hh + (size_t)l * HH * G2H, b_hh + (size_t)l * G2H,
        loglam + (size_t)l * HH,
        kW1 + (size_t)l * HH * K3H, kb1 + (size_t)l * K3H,
        kW2 + (size_t)l * K3H * HH, kb2 + (size_t)l * HH,
        tc, ti, tkk, hs);

    gemm_fp32<<<dim3(256, 8), 256, 0, stream>>>(
        hs, Wo + (size_t)l * HH * DD, nullptr, cout,
        BB * LSEQ, DD, HH);
  }
}